// Round 3
// baseline (296.292 us; speedup 1.0000x reference)
//
#include <hip/hip_runtime.h>

#define Kk  16
#define Bb  2048
#define Dd  1024
#define dd_ 64
#define BT  64          // b-rows per fused block
#define CH  64          // D chunk
#define NCH (Dd / CH)   // 16

// XOR swizzle: spreads transposed-stage rows across banks. sw(c)=4*((c>>2)&7).
__device__ __forceinline__ int swz(int c) { return ((c >> 2) & 7) << 2; }

// ---------------------------------------------------------------------------
// staging helpers (register prefetch -> LDS write, split for pipelining)
// ---------------------------------------------------------------------------
__device__ __forceinline__ void enc_load(const float* __restrict__ xk,
                                         const float* __restrict__ Usk,
                                         int Dc, int tx, int ty,
                                         float4 nx[4], float4 nu[4]) {
#pragma unroll
    for (int rr = 0; rr < 4; ++rr) {
        int row = rr * 16 + ty;
        nx[rr] = *reinterpret_cast<const float4*>(xk + (size_t)row * Dd + Dc + tx * 4);
        nu[rr] = *reinterpret_cast<const float4*>(Usk + (size_t)(Dc + row) * dd_ + tx * 4);
    }
}

__device__ __forceinline__ void enc_store(float (*bufT)[64], float (*bufS)[64],
                                          int tx, int ty,
                                          const float4 nx[4], const float4 nu[4]) {
    int sx = (tx & 7) << 2;              // swz(tx*4+c) is c-independent
#pragma unroll
    for (int rr = 0; rr < 4; ++rr) {
        int row = rr * 16 + ty;
        bufT[tx * 4 + 0][row ^ sx] = nx[rr].x;   // x^T, swizzled: 2-way max
        bufT[tx * 4 + 1][row ^ sx] = nx[rr].y;
        bufT[tx * 4 + 2][row ^ sx] = nx[rr].z;
        bufT[tx * 4 + 3][row ^ sx] = nx[rr].w;
        *reinterpret_cast<float4*>(&bufS[row][tx * 4]) = nu[rr];  // linear: free
    }
}

__device__ __forceinline__ void dec_load(const float* __restrict__ Usk,
                                         int Dc, int tx, int ty, float4 nU[4]) {
#pragma unroll
    for (int rr = 0; rr < 4; ++rr) {
        int row = rr * 16 + ty;
        nU[rr] = *reinterpret_cast<const float4*>(Usk + (size_t)(Dc + row) * dd_ + tx * 4);
    }
}

__device__ __forceinline__ void dec_store(float (*bufT)[64], int tx, int ty,
                                          const float4 nU[4]) {
    int sx = (tx & 7) << 2;
#pragma unroll
    for (int rr = 0; rr < 4; ++rr) {
        int row = rr * 16 + ty;
        bufT[tx * 4 + 0][row ^ sx] = nU[rr].x;   // Us^T, swizzled
        bufT[tx * 4 + 1][row ^ sx] = nU[rr].y;
        bufT[tx * 4 + 2][row ^ sx] = nU[rr].z;
        bufT[tx * 4 + 3][row ^ sx] = nU[rr].w;
    }
}

// ---------------------------------------------------------------------------
// Fused encode+decode per (k, 64-b tile):
//   z = x @ Us[k] (kept in LDS), x_ = z @ Us[k]^T (streamed), lterm = ||x_||^2-2||z||^2
// Pipelined: next chunk's global loads issue before compute, LDS writes after.
// ---------------------------------------------------------------------------
__global__ __launch_bounds__(256) void k_fused(const float* __restrict__ x,
                                               const float* __restrict__ Us,
                                               float* __restrict__ xhat,
                                               float* __restrict__ lterm) {
    __shared__ float bufT[CH][64];     // transposed operand (swizzled)
    __shared__ float bufS[CH][64];     // straight Us (encode b-frag)
    __shared__ float z_lds[dd_][68];   // z^T: [d][b], 68 keeps f4 align, pad
    __shared__ float zn_lds[BT];
    __shared__ float hat_lds[BT];

    int t  = threadIdx.x;
    int tx = t & 15;
    int ty = t >> 4;

    int bid = blockIdx.x;
    int sw  = (bid & 7) * 64 + (bid >> 3);   // XCD-aware, bijective (512%8==0)
    int k   = sw >> 5;
    int b0  = (sw & 31) * BT;

    const float* __restrict__ xk  = x  + (size_t)b0 * Dd;
    const float* __restrict__ Usk = Us + (size_t)k * Dd * dd_;

    if (t < BT) { zn_lds[t] = 0.f; hat_lds[t] = 0.f; }

    // ======== encode: acc[i][j] = sum_D x[b=tx*4+i][D] * Us[D][d=ty*4+j] ====
    float acc[4][4];
#pragma unroll
    for (int i = 0; i < 4; ++i)
#pragma unroll
        for (int j = 0; j < 4; ++j) acc[i][j] = 0.f;

    float4 nx[4], nu[4];
    enc_load(xk, Usk, 0, tx, ty, nx, nu);
    enc_store(bufT, bufS, tx, ty, nx, nu);
    __syncthreads();

    for (int ch = 0; ch < NCH; ++ch) {
        bool more = (ch + 1 < NCH);
        if (more) enc_load(xk, Usk, (ch + 1) * CH, tx, ty, nx, nu);  // in flight

#pragma unroll 8
        for (int kk = 0; kk < CH; ++kk) {
            float4 av = *reinterpret_cast<const float4*>(&bufT[kk][(tx * 4) ^ swz(kk)]);
            float4 bv = *reinterpret_cast<const float4*>(&bufS[kk][ty * 4]);
            float a_[4] = {av.x, av.y, av.z, av.w};
            float b_[4] = {bv.x, bv.y, bv.z, bv.w};
#pragma unroll
            for (int i = 0; i < 4; ++i)
#pragma unroll
                for (int j = 0; j < 4; ++j)
                    acc[i][j] = fmaf(a_[i], b_[j], acc[i][j]);
        }
        __syncthreads();
        if (more) { enc_store(bufT, bufS, tx, ty, nx, nu); __syncthreads(); }
    }

    // z tile -> LDS transposed; znorm partials from registers
#pragma unroll
    for (int i = 0; i < 4; ++i) {
        float pz = 0.f;
#pragma unroll
        for (int j = 0; j < 4; ++j) {
            z_lds[ty * 4 + j][tx * 4 + i] = acc[i][j];
            pz = fmaf(acc[i][j], acc[i][j], pz);
        }
        atomicAdd(&zn_lds[tx * 4 + i], pz);
    }
    __syncthreads();

    // ======== decode: dacc[i][j] = sum_d z[b=ty*4+i][d] * Us[D=tx*4+j][d] ===
    float hat[4] = {0.f, 0.f, 0.f, 0.f};
    float4 nU[4];
    dec_load(Usk, 0, tx, ty, nU);
    dec_store(bufT, tx, ty, nU);
    __syncthreads();

    for (int ch = 0; ch < NCH; ++ch) {
        bool more = (ch + 1 < NCH);
        int  Dc   = ch * CH;
        if (more) dec_load(Usk, Dc + CH, tx, ty, nU);

        float dacc[4][4];
#pragma unroll
        for (int i = 0; i < 4; ++i)
#pragma unroll
            for (int j = 0; j < 4; ++j) dacc[i][j] = 0.f;

#pragma unroll 8
        for (int kk = 0; kk < dd_; ++kk) {
            float4 av = *reinterpret_cast<const float4*>(&z_lds[kk][ty * 4]);
            float4 bv = *reinterpret_cast<const float4*>(&bufT[kk][(tx * 4) ^ swz(kk)]);
            float a_[4] = {av.x, av.y, av.z, av.w};
            float b_[4] = {bv.x, bv.y, bv.z, bv.w};
#pragma unroll
            for (int i = 0; i < 4; ++i)
#pragma unroll
                for (int j = 0; j < 4; ++j)
                    dacc[i][j] = fmaf(a_[i], b_[j], dacc[i][j]);
        }

#pragma unroll
        for (int i = 0; i < 4; ++i) {
            float4 o = make_float4(dacc[i][0], dacc[i][1], dacc[i][2], dacc[i][3]);
            *reinterpret_cast<float4*>(
                xhat + (size_t)(k * Bb + b0 + ty * 4 + i) * Dd + Dc + tx * 4) = o;
            hat[i] = fmaf(o.x, o.x, hat[i]);
            hat[i] = fmaf(o.y, o.y, hat[i]);
            hat[i] = fmaf(o.z, o.z, hat[i]);
            hat[i] = fmaf(o.w, o.w, hat[i]);
        }
        __syncthreads();
        if (more) { dec_store(bufT, tx, ty, nU); __syncthreads(); }
    }

#pragma unroll
    for (int i = 0; i < 4; ++i) atomicAdd(&hat_lds[ty * 4 + i], hat[i]);
    __syncthreads();
    if (t < BT) lterm[k * Bb + b0 + t] = hat_lds[t] - 2.f * zn_lds[t];
}

// ---------------------------------------------------------------------------
// Assign (xnorm folded in): 8 blocks x 256 thr. Wave-per-row xnorm, then
// per-thread argmin over lterm; per-block partial cnt/obj (no global atomics).
// ---------------------------------------------------------------------------
__global__ __launch_bounds__(256) void k_assign(const float* __restrict__ x,
                                                const float* __restrict__ lterm,
                                                float* __restrict__ c,
                                                float* __restrict__ cnt_part,
                                                float* __restrict__ obj_part) {
    __shared__ float xn_lds[256];
    __shared__ float cnt[Kk];
    __shared__ float objacc;
    int t    = threadIdx.x;
    int lane = t & 63;
    int w    = t >> 6;
    int bbase = blockIdx.x * 256;

    if (t < Kk) cnt[t] = 0.f;
    if (t == 0) objacc = 0.f;

    // xnorm: wave w covers local rows w*64 .. w*64+63, one row per pass
    for (int r = 0; r < 64; ++r) {
        int bl = w * 64 + r;
        const float* xr = x + (size_t)(bbase + bl) * Dd;
        float s = 0.f;
#pragma unroll
        for (int seg = 0; seg < 4; ++seg) {
            float4 v = *reinterpret_cast<const float4*>(xr + seg * 256 + lane * 4);
            s = fmaf(v.x, v.x, s); s = fmaf(v.y, v.y, s);
            s = fmaf(v.z, v.z, s); s = fmaf(v.w, v.w, s);
        }
#pragma unroll
        for (int off = 32; off > 0; off >>= 1) s += __shfl_down(s, off, 64);
        if (lane == 0) xn_lds[bl] = s;
    }
    __syncthreads();

    int b = bbase + t;
    float xn = xn_lds[t];
    float best = 3.4e38f;
    int   bi   = 0;
#pragma unroll
    for (int k = 0; k < Kk; ++k) {
        float l = xn + lterm[k * Bb + b];        // coalesced per k
        if (l < best) { best = l; bi = k; }      // strict < == first argmin
    }
#pragma unroll
    for (int j = 0; j < 4; ++j) {
        float4 o;
        o.x = (bi == j * 4 + 0) ? 1.f : 0.f;
        o.y = (bi == j * 4 + 1) ? 1.f : 0.f;
        o.z = (bi == j * 4 + 2) ? 1.f : 0.f;
        o.w = (bi == j * 4 + 3) ? 1.f : 0.f;
        *reinterpret_cast<float4*>(&c[(size_t)b * Kk + j * 4]) = o;
    }
    atomicAdd(&cnt[bi], 1.f);

    float lobj = best;
#pragma unroll
    for (int off = 32; off > 0; off >>= 1) lobj += __shfl_down(lobj, off, 64);
    if (lane == 0) atomicAdd(&objacc, lobj);
    __syncthreads();

    if (t < Kk) cnt_part[blockIdx.x * Kk + t] = cnt[t];
    if (t == 0) obj_part[blockIdx.x] = objacc;
}

// ---------------------------------------------------------------------------
__global__ __launch_bounds__(64) void k_final(const float* __restrict__ cnt_part,
                                              const float* __restrict__ obj_part,
                                              const float* __restrict__ c_mean,
                                              float* __restrict__ c_mean_new,
                                              float* __restrict__ obj) {
    int t = threadIdx.x;
    if (t < Kk) {
        float s = 0.f;
#pragma unroll
        for (int p = 0; p < 8; ++p) s += cnt_part[p * Kk + t];
        c_mean_new[t] = 0.9f * c_mean[t] + 0.1f * (s * (1.f / Bb));
    }
    if (t == 0) {
        float s = 0.f;
#pragma unroll
        for (int p = 0; p < 8; ++p) s += obj_part[p];
        obj[0] = s * (1.f / Bb);
    }
}

// ---------------------------------------------------------------------------
extern "C" void kernel_launch(void* const* d_in, const int* in_sizes, int n_in,
                              void* d_out, int out_size, void* d_ws, size_t ws_size,
                              hipStream_t stream) {
    const float* x      = (const float*)d_in[0];
    const float* Us     = (const float*)d_in[1];
    const float* c_mean = (const float*)d_in[2];

    float* out        = (float*)d_out;
    float* xhat       = out;                              // K*B*D
    float* c          = out + (size_t)Kk * Bb * Dd;       // B*K
    float* c_mean_new = c + (size_t)Bb * Kk;              // K
    float* obj        = c_mean_new + Kk;                  // 1

    float* ws       = (float*)d_ws;
    float* lterm    = ws;                                 // K*B
    float* cnt_part = lterm + (size_t)Kk * Bb;            // 8*K
    float* obj_part = cnt_part + 8 * Kk;                  // 8

    k_fused <<<Kk * (Bb / BT), 256, 0, stream>>>(x, Us, xhat, lterm);
    k_assign<<<Bb / 256, 256, 0, stream>>>(x, lterm, c, cnt_part, obj_part);
    k_final <<<1, 64, 0, stream>>>(cnt_part, obj_part, c_mean, c_mean_new, obj);
}